// Round 1
// baseline (2105.381 us; speedup 1.0000x reference)
//
#include <hip/hip_runtime.h>
#include <hip/hip_bf16.h>
#include <float.h>

#define DIM      256
#define KCODES   4096
#define BROWS    8            // rows per block
#define KPT      4            // codes per thread per chunk
#define NTHREADS 256
#define CHUNK    (NTHREADS * KPT)    // 1024
#define NCHUNK   (KCODES / CHUNK)    // 4
#define NSEQ     2048                // N
#define QOFF     4194304             // B*DIM*N
#define IDXOFF   4194304
#define LOSS_OFF 4210688
// loss scale: 0.25 / (B*N*DIM)
#define LOSS_SCALE (0.25f / 4194304.0f)

// Prep: codebook squared norms (float64) into d_ws; zero the loss slot.
__global__ __launch_bounds__(256) void fsq_prep(const float* __restrict__ cb,
                                                double* __restrict__ cnorm,
                                                float* __restrict__ out) {
  int code = blockIdx.x * 256 + threadIdx.x;
  const float4* c4 = reinterpret_cast<const float4*>(cb + (size_t)code * DIM);
  double s = 0.0;
#pragma unroll 8
  for (int i = 0; i < DIM / 4; ++i) {
    float4 v = c4[i];
    s += (double)v.x * v.x + (double)v.y * v.y + (double)v.z * v.z + (double)v.w * v.w;
  }
  cnorm[code] = s;
  if (blockIdx.x == 0 && threadIdx.x == 0) out[LOSS_OFF] = 0.0f;
}

__global__ __launch_bounds__(256) void fsq_main(const float* __restrict__ x,
                                                const float* __restrict__ cb,
                                                const double* __restrict__ cnorm,
                                                float* __restrict__ out) {
  __shared__ float xt[BROWS][DIM + 4];
  __shared__ float qt[BROWS][DIM + 4];
  __shared__ double wred_v[4][BROWS];
  __shared__ int    wred_i[4][BROWS];
  __shared__ int    sIdx[BROWS];
  __shared__ float  wloss[4];

  const int t   = threadIdx.x;
  const int blk = blockIdx.x;
  const int b   = blk >> 8;               // 2048/8 = 256 blocks per batch
  const int n0  = (blk & 255) * BROWS;

  // ---- stage x tile: xt[j][d] = x[b, d, n0+j] ----
  {
    const int j  = t & 7;
    const int d0 = t >> 3;                // 0..31
#pragma unroll
    for (int p = 0; p < 8; ++p) {
      int d = d0 + p * 32;
      xt[j][d] = x[(((size_t)b << 8) + d) * NSEQ + n0 + j];
    }
  }
  __syncthreads();

  double minv[BROWS];
  int    mini[BROWS];
#pragma unroll
  for (int r = 0; r < BROWS; ++r) { minv[r] = DBL_MAX; mini[r] = 0; }

  // ---- main scoring loop: score(k) = ||c_k||^2 - 2 * x.c_k  (float64) ----
  for (int c = 0; c < NCHUNK; ++c) {
    const int kbase = c * CHUNK + t * KPT;
    const float4* cbp = reinterpret_cast<const float4*>(cb + (size_t)kbase * DIM);

    double acc[BROWS][KPT];
#pragma unroll
    for (int r = 0; r < BROWS; ++r)
#pragma unroll
      for (int j = 0; j < KPT; ++j) acc[r][j] = 0.0;

#pragma unroll 2
    for (int d4 = 0; d4 < DIM / 4; ++d4) {
      float4 cv[KPT];
#pragma unroll
      for (int j = 0; j < KPT; ++j) cv[j] = cbp[j * (DIM / 4) + d4];
      float4 xv[BROWS];
#pragma unroll
      for (int r = 0; r < BROWS; ++r)
        xv[r] = *reinterpret_cast<const float4*>(&xt[r][d4 * 4]);
#pragma unroll
      for (int r = 0; r < BROWS; ++r) {
#pragma unroll
        for (int j = 0; j < KPT; ++j) {
          acc[r][j] += (double)xv[r].x * (double)cv[j].x;
          acc[r][j] += (double)xv[r].y * (double)cv[j].y;
          acc[r][j] += (double)xv[r].z * (double)cv[j].z;
          acc[r][j] += (double)xv[r].w * (double)cv[j].w;
        }
      }
    }

#pragma unroll
    for (int j = 0; j < KPT; ++j) {
      int k = kbase + j;
      double cn = cnorm[k];
#pragma unroll
      for (int r = 0; r < BROWS; ++r) {
        double dist = cn - 2.0 * acc[r][j];
        if (dist < minv[r] || (dist == minv[r] && k < mini[r])) {
          minv[r] = dist;
          mini[r] = k;
        }
      }
    }
  }

  // ---- wave-level argmin reduce (64 lanes) ----
#pragma unroll
  for (int r = 0; r < BROWS; ++r) {
    double v = minv[r];
    int    i = mini[r];
#pragma unroll
    for (int off = 1; off < 64; off <<= 1) {
      double ov = __shfl_xor(v, off, 64);
      int    oi = __shfl_xor(i, off, 64);
      if (ov < v || (ov == v && oi < i)) { v = ov; i = oi; }
    }
    minv[r] = v;
    mini[r] = i;
  }
  const int lane = t & 63;
  const int wv   = t >> 6;
  if (lane == 0) {
#pragma unroll
    for (int r = 0; r < BROWS; ++r) {
      wred_v[wv][r] = minv[r];
      wred_i[wv][r] = mini[r];
    }
  }
  __syncthreads();

  // ---- final cross-wave reduce + index output (threads 0..7, one per row) ----
  if (t < BROWS) {
    double v = wred_v[0][t];
    int    i = wred_i[0][t];
#pragma unroll
    for (int w = 1; w < 4; ++w) {
      double ov = wred_v[w][t];
      int    oi = wred_i[w][t];
      if (ov < v || (ov == v && oi < i)) { v = ov; i = oi; }
    }
    sIdx[t] = i;
    out[IDXOFF + (size_t)b * NSEQ + n0 + t] = (float)i;  // indices as float32
  }
  __syncthreads();

  // ---- gather quantized into LDS + commitment loss partial ----
  float lsum = 0.f;
#pragma unroll
  for (int r = 0; r < BROWS; ++r) {
    int idx = sIdx[r];
    float cv = cb[(size_t)idx * DIM + t];   // coalesced row read
    qt[r][t] = cv;
    float dx = cv - xt[r][t];
    lsum += dx * dx;
  }
  __syncthreads();

  // ---- write quantized [B, DIM, N]: lanes vary over rows for coalescing ----
  {
    const int r    = t & 7;
    const int dsub = (t >> 3) & 7;
    const int w    = t >> 6;
#pragma unroll
    for (int i = 0; i < 8; ++i) {
      int d = i * 32 + w * 8 + dsub;
      out[(((size_t)b << 8) + d) * NSEQ + n0 + r] = qt[r][d];
    }
  }

  // ---- loss reduce ----
#pragma unroll
  for (int off = 32; off > 0; off >>= 1) lsum += __shfl_xor(lsum, off, 64);
  if (lane == 0) wloss[wv] = lsum;
  __syncthreads();
  if (t == 0) {
    float total = wloss[0] + wloss[1] + wloss[2] + wloss[3];
    atomicAdd(out + LOSS_OFF, total * LOSS_SCALE);
  }
}

extern "C" void kernel_launch(void* const* d_in, const int* in_sizes, int n_in,
                              void* d_out, int out_size, void* d_ws, size_t ws_size,
                              hipStream_t stream) {
  const float* x  = (const float*)d_in[0];   // [8, 256, 2048] f32
  const float* cb = (const float*)d_in[1];   // [4096, 256] f32
  float* out = (float*)d_out;
  double* cnorm = (double*)d_ws;             // 4096 doubles = 32 KB

  fsq_prep<<<KCODES / 256, 256, 0, stream>>>(cb, cnorm, out);
  fsq_main<<<16384 / BROWS, 256, 0, stream>>>(x, cb, cnorm, out);
}

// Round 2
// 1801.324 us; speedup vs baseline: 1.1688x; 1.1688x over previous
//
#include <hip/hip_runtime.h>
#include <float.h>

#define DIM      256
#define KCODES   4096
#define NSEQ     2048
#define BROWS    16            // rows per block
#define KPT      4             // codes per thread per chunk
#define CHUNK    (256 * KPT)   // 1024
#define NCHUNK   (KCODES / CHUNK)
#define IDXOFF   4194304
#define LOSS_OFF 4210688
#define PAD      4
#define THRESH   2.0e-3f       // rescreen gap threshold (f32 err bound ~2e-4)

// ---------------- prep: codebook norms (f32 + f64), zero ws loss ----------
__global__ __launch_bounds__(256) void fsq_prep(const float* __restrict__ cb,
                                                float* __restrict__ cn32,
                                                double* __restrict__ cn64,
                                                double* __restrict__ wsloss) {
  int code = blockIdx.x * 256 + threadIdx.x;
  const float4* c4 = reinterpret_cast<const float4*>(cb + (size_t)code * DIM);
  double s = 0.0;
#pragma unroll 8
  for (int i = 0; i < DIM / 4; ++i) {
    float4 v = c4[i];
    s += (double)v.x * v.x + (double)v.y * v.y + (double)v.z * v.z + (double)v.w * v.w;
  }
  cn32[code] = (float)s;
  cn64[code] = s;
  if (code == 0) *wsloss = 0.0;
}

// ---------------- pass 1: f32 scoring, top-2 tracking, flag near-ties -----
__global__ __launch_bounds__(256, 3) void fsq_score(const float* __restrict__ x,
                                                    const float* __restrict__ cb,
                                                    const float* __restrict__ cn32,
                                                    int* __restrict__ idxws) {
  __shared__ float xt[BROWS][DIM + PAD];
  __shared__ float w1[4][BROWS], w2[4][BROWS];
  __shared__ int   wi[4][BROWS];

  const int t  = threadIdx.x;
  const int g0 = blockIdx.x * BROWS;          // first global row of block
  const int b  = g0 >> 11;                    // row / 2048
  const int n0 = g0 & (NSEQ - 1);

  // stage x tile: xt[j][d] = x[b, d, n0+j]
  {
    const int j  = t & 15;
    const int d0 = t >> 4;                    // 0..15
#pragma unroll
    for (int p = 0; p < 16; ++p) {
      int d = d0 * 16 + p;
      xt[j][d] = x[(((size_t)b << 8) + d) * NSEQ + n0 + j];
    }
  }
  __syncthreads();

  float v1[BROWS], v2[BROWS];
  int   i1[BROWS];
#pragma unroll
  for (int r = 0; r < BROWS; ++r) { v1[r] = FLT_MAX; v2[r] = FLT_MAX; i1[r] = 0; }

  for (int c = 0; c < NCHUNK; ++c) {
    const int kbase = c * CHUNK + t * KPT;
    const float4* cbp = reinterpret_cast<const float4*>(cb + (size_t)kbase * DIM);

    float acc[BROWS][KPT];
#pragma unroll
    for (int r = 0; r < BROWS; ++r)
#pragma unroll
      for (int j = 0; j < KPT; ++j) acc[r][j] = 0.f;

#pragma unroll 2
    for (int d4 = 0; d4 < DIM / 4; ++d4) {
      float4 cv[KPT];
#pragma unroll
      for (int j = 0; j < KPT; ++j) cv[j] = cbp[j * (DIM / 4) + d4];
#pragma unroll
      for (int r = 0; r < BROWS; ++r) {
        float4 xv = *reinterpret_cast<const float4*>(&xt[r][d4 * 4]);
#pragma unroll
        for (int j = 0; j < KPT; ++j) {
          acc[r][j] = fmaf(xv.x, cv[j].x, acc[r][j]);
          acc[r][j] = fmaf(xv.y, cv[j].y, acc[r][j]);
          acc[r][j] = fmaf(xv.z, cv[j].z, acc[r][j]);
          acc[r][j] = fmaf(xv.w, cv[j].w, acc[r][j]);
        }
      }
    }

#pragma unroll
    for (int j = 0; j < KPT; ++j) {
      int k = kbase + j;
      float cn = cn32[k];
#pragma unroll
      for (int r = 0; r < BROWS; ++r) {
        float dist = fmaf(-2.f, acc[r][j], cn);
        if (dist < v1[r]) { v2[r] = v1[r]; v1[r] = dist; i1[r] = k; }
        else if (dist < v2[r]) { v2[r] = dist; }
      }
    }
  }

  // wave-level top-2 merge (64 lanes)
  const int lane = t & 63;
  const int wv   = t >> 6;
#pragma unroll
  for (int r = 0; r < BROWS; ++r) {
    float a1 = v1[r], a2 = v2[r];
    int   ai = i1[r];
#pragma unroll
    for (int off = 1; off < 64; off <<= 1) {
      float o1 = __shfl_xor(a1, off, 64);
      float o2 = __shfl_xor(a2, off, 64);
      int   oi = __shfl_xor(ai, off, 64);
      if (o1 < a1 || (o1 == a1 && oi < ai)) { a2 = fminf(a1, o2); a1 = o1; ai = oi; }
      else { a2 = fminf(a2, o1); }
    }
    if (lane == 0) { w1[wv][r] = a1; w2[wv][r] = a2; wi[wv][r] = ai; }
  }
  __syncthreads();

  if (t < BROWS) {
    float a1 = w1[0][t], a2 = w2[0][t];
    int   ai = wi[0][t];
#pragma unroll
    for (int w = 1; w < 4; ++w) {
      float o1 = w1[w][t], o2 = w2[w][t];
      int   oi = wi[w][t];
      if (o1 < a1 || (o1 == a1 && oi < ai)) { a2 = fminf(a1, o2); a1 = o1; ai = oi; }
      else { a2 = fminf(a2, o1); }
    }
    // flag near-ties by negative encoding
    idxws[g0 + t] = (a2 - a1 < THRESH) ? -(ai + 1) : ai;
  }
}

// ---------------- pass 2: f64 rescreen of flagged rows + outputs ----------
__global__ __launch_bounds__(256) void fsq_out(const float* __restrict__ x,
                                               const float* __restrict__ cb,
                                               const double* __restrict__ cn64,
                                               const int* __restrict__ idxws,
                                               float* __restrict__ out,
                                               double* __restrict__ wsloss) {
  __shared__ float xt[BROWS][DIM + PAD];
  __shared__ float qt[BROWS][DIM + PAD];
  __shared__ int   sIdx[BROWS];
  __shared__ int   sFlag;
  __shared__ double rv[4];
  __shared__ int    ri[4];
  __shared__ double wl[4];

  const int t  = threadIdx.x;
  const int g0 = blockIdx.x * BROWS;
  const int b  = g0 >> 11;
  const int n0 = g0 & (NSEQ - 1);
  const int lane = t & 63;
  const int wv   = t >> 6;

  if (t == 0) sFlag = 0;
  // stage x tile
  {
    const int j  = t & 15;
    const int d0 = t >> 4;
#pragma unroll
    for (int p = 0; p < 16; ++p) {
      int d = d0 * 16 + p;
      xt[j][d] = x[(((size_t)b << 8) + d) * NSEQ + n0 + j];
    }
  }
  __syncthreads();   // covers sFlag=0 too

  if (t < BROWS) {
    int v = idxws[g0 + t];
    if (v < 0) { atomicOr(&sFlag, 1 << t); sIdx[t] = -(v + 1); }
    else       { sIdx[t] = v; }
  }
  __syncthreads();

  int fl = sFlag;
  while (fl) {
    int fr = __ffs(fl) - 1;
    fl &= fl - 1;
    // exact f64 argmin over all codes for row fr
    double best = DBL_MAX;
    int    bi   = 0;
    const float4* xr = reinterpret_cast<const float4*>(&xt[fr][0]);
#pragma unroll 1
    for (int c = 0; c < 16; ++c) {
      int k = t + (c << 8);
      const float4* cp = reinterpret_cast<const float4*>(cb + (size_t)k * DIM);
      double dot = 0.0;
#pragma unroll 4
      for (int d4 = 0; d4 < DIM / 4; ++d4) {
        float4 cv = cp[d4];
        float4 xv = xr[d4];
        dot += (double)xv.x * cv.x + (double)xv.y * cv.y +
               (double)xv.z * cv.z + (double)xv.w * cv.w;
      }
      double dist = cn64[k] - 2.0 * dot;
      if (dist < best || (dist == best && k < bi)) { best = dist; bi = k; }
    }
#pragma unroll
    for (int off = 1; off < 64; off <<= 1) {
      double ob = __shfl_xor(best, off, 64);
      int    oi = __shfl_xor(bi, off, 64);
      if (ob < best || (ob == best && oi < bi)) { best = ob; bi = oi; }
    }
    if (lane == 0) { rv[wv] = best; ri[wv] = bi; }
    __syncthreads();
    if (t == 0) {
      double bb = rv[0]; int ii = ri[0];
#pragma unroll
      for (int w = 1; w < 4; ++w) {
        if (rv[w] < bb || (rv[w] == bb && ri[w] < ii)) { bb = rv[w]; ii = ri[w]; }
      }
      sIdx[fr] = ii;
    }
    __syncthreads();
  }

  // gather + loss partial (t is the dim index)
  float lsum = 0.f;
#pragma unroll
  for (int r = 0; r < BROWS; ++r) {
    int idx = sIdx[r];
    float cv = cb[(size_t)idx * DIM + t];      // coalesced
    qt[r][t] = cv;
    float dx = cv - xt[r][t];
    lsum += dx * dx;
  }
  __syncthreads();

  // quantized output [B, DIM, N], coalesced over rows
  {
    const int r    = t & 15;
    const int dcol = t >> 4;
#pragma unroll
    for (int i = 0; i < 16; ++i) {
      int d = i * 16 + dcol;
      out[(((size_t)b << 8) + d) * NSEQ + n0 + r] = qt[r][d];
    }
  }
  // indices as f32
  if (t < BROWS) out[IDXOFF + g0 + t] = (float)sIdx[t];

  // loss reduce (f32 within wave, f64 across)
#pragma unroll
  for (int off = 32; off > 0; off >>= 1) lsum += __shfl_xor(lsum, off, 64);
  if (lane == 0) wl[wv] = (double)lsum;
  __syncthreads();
  if (t == 0) atomicAdd(wsloss, wl[0] + wl[1] + wl[2] + wl[3]);
}

// ---------------- pass 3: finalize loss ----------------
__global__ void fsq_finish(const double* __restrict__ wsloss, float* __restrict__ out) {
  if (threadIdx.x == 0)
    out[LOSS_OFF] = (float)(*wsloss * (0.25 / 4194304.0));
}

extern "C" void kernel_launch(void* const* d_in, const int* in_sizes, int n_in,
                              void* d_out, int out_size, void* d_ws, size_t ws_size,
                              hipStream_t stream) {
  const float* x  = (const float*)d_in[0];   // [8, 256, 2048]
  const float* cb = (const float*)d_in[1];   // [4096, 256]
  float* out = (float*)d_out;

  char* wsb = (char*)d_ws;
  double* wsloss = (double*)wsb;                       // 8 B
  float*  cn32   = (float*)(wsb + 16);                 // 16 KB
  double* cn64   = (double*)(wsb + 16 + 16384);        // 32 KB
  int*    idxws  = (int*)(wsb + 16 + 16384 + 32768);   // 64 KB

  fsq_prep<<<KCODES / 256, 256, 0, stream>>>(cb, cn32, cn64, wsloss);
  fsq_score<<<16384 / BROWS, 256, 0, stream>>>(x, cb, cn32, idxws);
  fsq_out<<<16384 / BROWS, 256, 0, stream>>>(x, cb, cn64, idxws, out, wsloss);
  fsq_finish<<<1, 64, 0, stream>>>(wsloss, out);
}

// Round 3
// 502.156 us; speedup vs baseline: 4.1927x; 3.5872x over previous
//
#include <hip/hip_runtime.h>
#include <float.h>

#define DIM      256
#define KCODES   4096
#define NSEQ     2048
#define IDXOFF   4194304
#define LOSS_OFF 4210688

#define MROWS    64            // rows per fsq_score block
#define TCODES   64            // codes per LDS tile
#define NTILE    (KCODES / TCODES)
#define THRESH   1.0e-3f       // split-bf16 dist err ~1e-5 -> 100x margin
#define RCAP     1024
#define PAD      4

typedef __attribute__((ext_vector_type(8))) short short8;
typedef __attribute__((ext_vector_type(4))) float f32x4;
typedef __attribute__((ext_vector_type(4))) unsigned short us4;

// f32 -> bf16(hi) + bf16(lo) split, RNE
__device__ __forceinline__ void bsplit(float x, unsigned short& hi, unsigned short& lo) {
  union { float f; unsigned u; } a; a.f = x;
  unsigned r = a.u + 0x7FFFu + ((a.u >> 16) & 1u);
  hi = (unsigned short)(r >> 16);
  union { unsigned u; float f; } h; h.u = ((unsigned)hi) << 16;
  float res = x - h.f;
  union { float f; unsigned u; } b; b.f = res;
  unsigned r2 = b.u + 0x7FFFu + ((b.u >> 16) & 1u);
  lo = (unsigned short)(r2 >> 16);
}

// ---------------- prep: codebook norms + zero accumulators ----------------
__global__ __launch_bounds__(256) void fsq_prep(const float* __restrict__ cb,
                                                float* __restrict__ cn32,
                                                double* __restrict__ cn64,
                                                double* __restrict__ wsloss,
                                                int* __restrict__ rcount) {
  int code = blockIdx.x * 256 + threadIdx.x;
  const float4* c4 = reinterpret_cast<const float4*>(cb + (size_t)code * DIM);
  double s = 0.0;
#pragma unroll 8
  for (int i = 0; i < DIM / 4; ++i) {
    float4 v = c4[i];
    s += (double)v.x * v.x + (double)v.y * v.y + (double)v.z * v.z + (double)v.w * v.w;
  }
  cn32[code] = (float)s;
  cn64[code] = s;
  if (code == 0) { *wsloss = 0.0; *rcount = 0; }
}

// -------- pass 1: split-bf16 MFMA screen, top-2 per row, flag near-ties ----
__global__ __launch_bounds__(256, 1) void fsq_score(
    const float* __restrict__ x, const float* __restrict__ cb,
    const float* __restrict__ cn32, int* __restrict__ idxws,
    int* __restrict__ rcount, int* __restrict__ rlist) {
  __shared__ unsigned short bhi[2][TCODES * DIM];   // 64 KB
  __shared__ unsigned short blo[2][TCODES * DIM];   // 64 KB

  const int t   = threadIdx.x;
  const int l   = t & 63;
  const int wid = t >> 6;
  const int g0  = blockIdx.x * MROWS;
  const int b   = g0 >> 11;
  const int n0  = g0 & (NSEQ - 1);
  const int col = l & 15;
  const int kg  = l >> 4;

  // ---- A fragments (16 rows/wave x 256 dims), split bf16, kept in regs ----
  short8 ahi[8], alo[8];
  {
    const int nrow = n0 + wid * 16 + col;
    const float* xb = x + (size_t)(b << 8) * NSEQ + nrow;
#pragma unroll
    for (int st = 0; st < 8; ++st) {
      float av[8];
#pragma unroll
      for (int j = 0; j < 8; ++j) {
        int d = st * 32 + kg * 8 + j;
        av[j] = xb[(size_t)d * NSEQ];
      }
      short8 h8, l8;
#pragma unroll
      for (int j = 0; j < 8; ++j) {
        unsigned short hh, ll;
        bsplit(av[j], hh, ll);
        h8[j] = (short)hh; l8[j] = (short)ll;
      }
      ahi[st] = h8; alo[st] = l8;
    }
  }

  const int cl = t >> 2;   // code-local 0..63 (staging)
  const int dq = t & 3;    // dim quarter   (staging)

  // ---- stage tile 0 into buffer 0 ----
  {
    const float4* p = (const float4*)(cb + (size_t)cl * DIM + dq * 64);
    float4 pf[16];
#pragma unroll
    for (int i = 0; i < 16; ++i) pf[i] = p[i];
#pragma unroll
    for (int i = 0; i < 16; ++i) {
      us4 hv, lv;
      float vv0 = pf[i].x, vv1 = pf[i].y, vv2 = pf[i].z, vv3 = pf[i].w;
      unsigned short hh, ll;
      bsplit(vv0, hh, ll); hv[0] = hh; lv[0] = ll;
      bsplit(vv1, hh, ll); hv[1] = hh; lv[1] = ll;
      bsplit(vv2, hh, ll); hv[2] = hh; lv[2] = ll;
      bsplit(vv3, hh, ll); hv[3] = hh; lv[3] = ll;
      int byteoff = cl * 512 + dq * 128 + i * 8;
      byteoff ^= (cl & 7) << 4;                       // bank swizzle
      *(us4*)((char*)&bhi[0][0] + byteoff) = hv;
      *(us4*)((char*)&blo[0][0] + byteoff) = lv;
    }
  }
  __syncthreads();

  float v1[4], v2[4];
  int   i1[4];
#pragma unroll
  for (int r = 0; r < 4; ++r) { v1[r] = FLT_MAX; v2[r] = FLT_MAX; i1[r] = 0; }

  int cur = 0;
  for (int ti = 0; ti < NTILE; ++ti) {
    const int kb = ti * TCODES;

    // prefetch next tile (issue early; consumed after MFMA phase)
    float4 pf[16];
    if (ti + 1 < NTILE) {
      const float4* p = (const float4*)(cb + (size_t)(kb + TCODES + cl) * DIM + dq * 64);
#pragma unroll
      for (int i = 0; i < 16; ++i) pf[i] = p[i];
    }

    // ---- MFMA: 4 col-groups x 8 k-subtiles x 3 passes ----
    f32x4 acc[4] = {{0,0,0,0},{0,0,0,0},{0,0,0,0},{0,0,0,0}};
#pragma unroll
    for (int st = 0; st < 8; ++st) {
#pragma unroll
      for (int cg = 0; cg < 4; ++cg) {
        int code_l = cg * 16 + col;
        int off = code_l * 512 + st * 64 + kg * 16;
        off ^= (code_l & 7) << 4;
        short8 bh = *(const short8*)((const char*)&bhi[cur][0] + off);
        short8 bl = *(const short8*)((const char*)&blo[cur][0] + off);
        acc[cg] = __builtin_amdgcn_mfma_f32_16x16x32_bf16(ahi[st], bh, acc[cg], 0, 0, 0);
        acc[cg] = __builtin_amdgcn_mfma_f32_16x16x32_bf16(alo[st], bh, acc[cg], 0, 0, 0);
        acc[cg] = __builtin_amdgcn_mfma_f32_16x16x32_bf16(ahi[st], bl, acc[cg], 0, 0, 0);
      }
    }

    // ---- epilogue: dist = cn - 2*dot, update per-row top-2 ----
#pragma unroll
    for (int cg = 0; cg < 4; ++cg) {
      int k = kb + cg * 16 + col;
      float cn = cn32[k];
#pragma unroll
      for (int r = 0; r < 4; ++r) {
        float dist = fmaf(-2.f, acc[cg][r], cn);
        if (dist < v1[r]) { v2[r] = v1[r]; v1[r] = dist; i1[r] = k; }
        else              { v2[r] = fminf(v2[r], dist); }
      }
    }

    // ---- convert + write prefetched tile into other buffer ----
    if (ti + 1 < NTILE) {
#pragma unroll
      for (int i = 0; i < 16; ++i) {
        us4 hv, lv;
        unsigned short hh, ll;
        bsplit(pf[i].x, hh, ll); hv[0] = hh; lv[0] = ll;
        bsplit(pf[i].y, hh, ll); hv[1] = hh; lv[1] = ll;
        bsplit(pf[i].z, hh, ll); hv[2] = hh; lv[2] = ll;
        bsplit(pf[i].w, hh, ll); hv[3] = hh; lv[3] = ll;
        int byteoff = cl * 512 + dq * 128 + i * 8;
        byteoff ^= (cl & 7) << 4;
        *(us4*)((char*)&bhi[cur ^ 1][0] + byteoff) = hv;
        *(us4*)((char*)&blo[cur ^ 1][0] + byteoff) = lv;
      }
    }
    __syncthreads();
    cur ^= 1;
  }

  // ---- merge top-2 across the 16 col-lanes sharing each row-group ----
#pragma unroll
  for (int r = 0; r < 4; ++r) {
    float a1 = v1[r], a2 = v2[r];
    int   ai = i1[r];
#pragma unroll
    for (int off = 1; off < 16; off <<= 1) {
      float o1 = __shfl_xor(a1, off, 64);
      float o2 = __shfl_xor(a2, off, 64);
      int   oi = __shfl_xor(ai, off, 64);
      if (o1 < a1 || (o1 == a1 && oi < ai)) { a2 = fminf(a1, o2); a1 = o1; ai = oi; }
      else                                  { a2 = fminf(a2, o1); }
    }
    v1[r] = a1; v2[r] = a2; i1[r] = ai;
  }

  if (col == 0) {
#pragma unroll
    for (int r = 0; r < 4; ++r) {
      int grow = g0 + wid * 16 + kg * 4 + r;   // C row = kg*4 + r
      bool flag = (v2[r] - v1[r]) < THRESH;
      idxws[grow] = flag ? -(i1[r] + 1) : i1[r];
      if (flag) {
        int p = atomicAdd(rcount, 1);
        if (p < RCAP) rlist[p] = grow;
      }
    }
  }
}

// -------- pass 2: exact f64 rescreen of flagged rows (one block per row) ---
__global__ __launch_bounds__(256) void fsq_rescreen(
    const float* __restrict__ x, const float* __restrict__ cb,
    const double* __restrict__ cn64, const int* __restrict__ rcount,
    const int* __restrict__ rlist, int* __restrict__ idxws) {
  __shared__ float  xrow[DIM];
  __shared__ double rv[4];
  __shared__ int    ri[4];

  const int t    = threadIdx.x;
  const int lane = t & 63;
  const int wv   = t >> 6;
  int cnt = *rcount;
  if (cnt > RCAP) cnt = RCAP;
  if (cnt < 0) cnt = 0;

  for (int i = blockIdx.x; i < cnt; i += gridDim.x) {
    const int row = rlist[i] & 16383;
    const int b   = row >> 11;
    const int n   = row & (NSEQ - 1);
    xrow[t] = x[((size_t)(b << 8) + t) * NSEQ + n];
    __syncthreads();

    double best = DBL_MAX;
    int    bi   = 0;
    const float4* xr = reinterpret_cast<const float4*>(&xrow[0]);
#pragma unroll 1
    for (int c = 0; c < 16; ++c) {
      int k = t + (c << 8);
      const float4* cp = reinterpret_cast<const float4*>(cb + (size_t)k * DIM);
      double dot = 0.0;
#pragma unroll 4
      for (int d4 = 0; d4 < DIM / 4; ++d4) {
        float4 cv = cp[d4];
        float4 xv = xr[d4];
        dot += (double)xv.x * cv.x + (double)xv.y * cv.y +
               (double)xv.z * cv.z + (double)xv.w * cv.w;
      }
      double dist = cn64[k] - 2.0 * dot;
      if (dist < best || (dist == best && k < bi)) { best = dist; bi = k; }
    }
#pragma unroll
    for (int off = 1; off < 64; off <<= 1) {
      double ob = __shfl_xor(best, off, 64);
      int    oi = __shfl_xor(bi, off, 64);
      if (ob < best || (ob == best && oi < bi)) { best = ob; bi = oi; }
    }
    if (lane == 0) { rv[wv] = best; ri[wv] = bi; }
    __syncthreads();
    if (t == 0) {
      double bb = rv[0]; int ii = ri[0];
#pragma unroll
      for (int w = 1; w < 4; ++w)
        if (rv[w] < bb || (rv[w] == bb && ri[w] < ii)) { bb = rv[w]; ii = ri[w]; }
      idxws[row] = ii;
    }
    __syncthreads();
  }
}

// -------- pass 3: gather + quantized write + indices + commit loss ---------
#define OROWS 16
__global__ __launch_bounds__(256) void fsq_out(const float* __restrict__ x,
                                               const float* __restrict__ cb,
                                               const int* __restrict__ idxws,
                                               float* __restrict__ out,
                                               double* __restrict__ wsloss) {
  __shared__ float xt[OROWS][DIM + PAD];
  __shared__ float qt[OROWS][DIM + PAD];
  __shared__ int   sIdx[OROWS];
  __shared__ double wl[4];

  const int t    = threadIdx.x;
  const int g0   = blockIdx.x * OROWS;
  const int b    = g0 >> 11;
  const int n0   = g0 & (NSEQ - 1);
  const int lane = t & 63;
  const int wv   = t >> 6;

  {
    const int j  = t & 15;
    const int d0 = t >> 4;
#pragma unroll
    for (int p = 0; p < 16; ++p) {
      int d = d0 * 16 + p;
      xt[j][d] = x[(((size_t)b << 8) + d) * NSEQ + n0 + j];
    }
  }
  if (t < OROWS) {
    int v = idxws[g0 + t];
    sIdx[t] = ((v < 0) ? -(v + 1) : v) & (KCODES - 1);
  }
  __syncthreads();

  float lsum = 0.f;
#pragma unroll
  for (int r = 0; r < OROWS; ++r) {
    int idx = sIdx[r];
    float cv = cb[(size_t)idx * DIM + t];
    qt[r][t] = cv;
    float dx = cv - xt[r][t];
    lsum += dx * dx;
  }
  __syncthreads();

  {
    const int r    = t & 15;
    const int dcol = t >> 4;
#pragma unroll
    for (int i = 0; i < 16; ++i) {
      int d = i * 16 + dcol;
      out[(((size_t)b << 8) + d) * NSEQ + n0 + r] = qt[r][d];
    }
  }
  if (t < OROWS) out[IDXOFF + g0 + t] = (float)sIdx[t];

#pragma unroll
  for (int off = 32; off > 0; off >>= 1) lsum += __shfl_xor(lsum, off, 64);
  if (lane == 0) wl[wv] = (double)lsum;
  __syncthreads();
  if (t == 0) atomicAdd(wsloss, wl[0] + wl[1] + wl[2] + wl[3]);
}

__global__ void fsq_finish(const double* __restrict__ wsloss, float* __restrict__ out) {
  if (threadIdx.x == 0)
    out[LOSS_OFF] = (float)(*wsloss * (0.25 / 4194304.0));
}

extern "C" void kernel_launch(void* const* d_in, const int* in_sizes, int n_in,
                              void* d_out, int out_size, void* d_ws, size_t ws_size,
                              hipStream_t stream) {
  const float* x  = (const float*)d_in[0];   // [8, 256, 2048]
  const float* cb = (const float*)d_in[1];   // [4096, 256]
  float* out = (float*)d_out;

  char* wsb = (char*)d_ws;
  double* wsloss = (double*)wsb;                    // @0
  int*    rcount = (int*)(wsb + 8);                 // @8
  float*  cn32   = (float*)(wsb + 4096);            // 16 KB
  double* cn64   = (double*)(wsb + 4096 + 16384);   // 32 KB
  int*    idxws  = (int*)(wsb + 4096 + 16384 + 32768);            // 64 KB
  int*    rlist  = (int*)(wsb + 4096 + 16384 + 32768 + 65536);    // 4 KB

  fsq_prep<<<KCODES / 256, 256, 0, stream>>>(cb, cn32, cn64, wsloss, rcount);
  fsq_score<<<16384 / MROWS, 256, 0, stream>>>(x, cb, cn32, idxws, rcount, rlist);
  fsq_rescreen<<<64, 256, 0, stream>>>(x, cb, cn64, rcount, rlist, idxws);
  fsq_out<<<16384 / OROWS, 256, 0, stream>>>(x, cb, idxws, out, wsloss);
  fsq_finish<<<1, 64, 0, stream>>>(wsloss, out);
}

// Round 4
// 335.195 us; speedup vs baseline: 6.2811x; 1.4981x over previous
//
#include <hip/hip_runtime.h>
#include <float.h>

#define DIM      256
#define KCODES   4096
#define NSEQ     2048
#define IDXOFF   4194304
#define LOSS_OFF 4210688
#define NTILE    64            // 64 codes per tile
#define THRESH   1.0e-3f
#define RCAP     1024

typedef __attribute__((ext_vector_type(8))) short short8;
typedef __attribute__((ext_vector_type(4))) float f32x4;

// f32 -> bf16(hi) + bf16(lo) split, RNE
__device__ __forceinline__ void bsplit(float x, unsigned short& hi, unsigned short& lo) {
  union { float f; unsigned u; } a; a.f = x;
  unsigned r = a.u + 0x7FFFu + ((a.u >> 16) & 1u);
  hi = (unsigned short)(r >> 16);
  union { unsigned u; float f; } h; h.u = ((unsigned)hi) << 16;
  float res = x - h.f;
  union { float f; unsigned u; } b2; b2.f = res;
  unsigned r2 = b2.u + 0x7FFFu + ((b2.u >> 16) & 1u);
  lo = (unsigned short)(r2 >> 16);
}

__device__ __forceinline__ void gload_lds16(const void* g, void* l) {
  __builtin_amdgcn_global_load_lds(
      (const __attribute__((address_space(1))) unsigned*)g,
      (__attribute__((address_space(3))) unsigned*)l, 16, 0, 0);
}

// ---------------- prep A: codebook norms + zero accumulators ----------------
__global__ __launch_bounds__(256) void fsq_prep(const float* __restrict__ cb,
                                                float* __restrict__ cn32,
                                                double* __restrict__ cn64,
                                                double* __restrict__ wsloss,
                                                int* __restrict__ rcount) {
  int code = blockIdx.x * 256 + threadIdx.x;
  const float4* c4 = reinterpret_cast<const float4*>(cb + (size_t)code * DIM);
  double s = 0.0;
#pragma unroll 8
  for (int i = 0; i < DIM / 4; ++i) {
    float4 v = c4[i];
    s += (double)v.x * v.x + (double)v.y * v.y + (double)v.z * v.z + (double)v.w * v.w;
  }
  cn32[code] = (float)s;
  cn64[code] = s;
  if (code == 0) { *wsloss = 0.0; *rcount = 0; }
}

// ---------------- prep B: split codebook into MFMA-fragment-linear order ----
// Per 64-code tile (64 KB): hi region 32 KB then lo region 32 KB.
// chunk c (16B) = frag*64 + l, frag = ch*16 + st*2 + cg, l = kg*16 + col.
// data = cb[ti*64 + ch*32 + cg*16 + col][st*32 + kg*8 + j], j=0..7.
__global__ __launch_bounds__(256) void fsq_perm(const float* __restrict__ cb,
                                                char* __restrict__ cbsplit) {
  int tid = blockIdx.x * 256 + threadIdx.x;      // 0..131071 (hi chunks)
  int ti  = tid >> 11;
  int c   = tid & 2047;
  int frag = c >> 6, ll = c & 63;
  int chh = frag >> 4, stt = (frag >> 1) & 7, cgg = frag & 1;
  int kgg = ll >> 4,  coll = ll & 15;
  int code  = ti * 64 + chh * 32 + cgg * 16 + coll;
  int dbase = stt * 32 + kgg * 8;
  const float4* p = (const float4*)(cb + (size_t)code * DIM + dbase);
  float4 aa = p[0], bb = p[1];
  float vv[8] = {aa.x, aa.y, aa.z, aa.w, bb.x, bb.y, bb.z, bb.w};
  short8 h8, l8;
#pragma unroll
  for (int j = 0; j < 8; ++j) {
    unsigned short hh, lo2;
    bsplit(vv[j], hh, lo2);
    h8[j] = (short)hh; l8[j] = (short)lo2;
  }
  *(short8*)(cbsplit + (size_t)ti * 65536 + c * 16) = h8;
  *(short8*)(cbsplit + (size_t)ti * 65536 + 32768 + c * 16) = l8;
}

// ---- main: MFMA screen + top-2 + integrated gather/loss/output ------------
__global__ __launch_bounds__(512, 2) void fsq_score(
    const float* __restrict__ x, const float* __restrict__ cb,
    const char* __restrict__ cbsplit, const float* __restrict__ cn32,
    int* __restrict__ idxws, int* __restrict__ rcount, int* __restrict__ rlist,
    float* __restrict__ out, double* __restrict__ wsloss) {
  __shared__ __align__(16) short tiles[2][32768];   // 128 KB, dbuf
  __shared__ float m1[8][16], m2[8][16];
  __shared__ int   mi[8][16];
  __shared__ int   sIdx[64];
  __shared__ double wl[8];

  const int t   = threadIdx.x;
  const int wid = t >> 6;
  const int l   = t & 63;
  const int col = l & 15;
  const int kg  = l >> 4;
  const int rg  = wid & 3;       // row-group (16 rows each)
  const int ch  = wid >> 2;      // code-half of each tile
  const int g0  = blockIdx.x * 64;
  const int b   = g0 >> 11;
  const int n0  = g0 & (NSEQ - 1);

  // ---- A fragments: 16 rows/wave x 256 dims, split bf16 ----
  short8 ahi[8], alo[8];
  {
    const float* xb = x + (size_t)(b << 8) * NSEQ + (n0 + rg * 16 + col);
#pragma unroll
    for (int st = 0; st < 8; ++st) {
      short8 h8, l8;
#pragma unroll
      for (int j = 0; j < 8; ++j) {
        float v = xb[(size_t)(st * 32 + kg * 8 + j) * NSEQ];
        unsigned short hh, ll2;
        bsplit(v, hh, ll2);
        h8[j] = (short)hh; l8[j] = (short)ll2;
      }
      ahi[st] = h8; alo[st] = l8;
    }
  }

  // ---- prologue: stage tile 0 (linear, global_load_lds w16) ----
#pragma unroll
  for (int s = 0; s < 8; ++s)
    gload_lds16(cbsplit + s * 8192 + wid * 1024 + (l << 4),
                (char*)&tiles[0][0] + s * 8192 + wid * 1024);
  __syncthreads();

  float v1[4], v2[4]; int i1[4];
#pragma unroll
  for (int r = 0; r < 4; ++r) { v1[r] = FLT_MAX; v2[r] = FLT_MAX; i1[r] = 0; }

  int cur = 0;
  for (int ti = 0; ti < NTILE; ++ti) {
    // stage next tile into other buffer
    if (ti + 1 < NTILE) {
      const char* src = cbsplit + (size_t)(ti + 1) * 65536;
#pragma unroll
      for (int s = 0; s < 8; ++s)
        gload_lds16(src + s * 8192 + wid * 1024 + (l << 4),
                    (char*)&tiles[cur ^ 1][0] + s * 8192 + wid * 1024);
    }

    // compute current tile: frag reads are contiguous 1024B/wave (conflict-free)
    f32x4 acc[2] = {{0, 0, 0, 0}, {0, 0, 0, 0}};
    const char* base = (const char*)&tiles[cur][0] + ch * 16384 + (l << 4);
#pragma unroll
    for (int st = 0; st < 8; ++st) {
#pragma unroll
      for (int cg = 0; cg < 2; ++cg) {
        const char* p = base + st * 2048 + cg * 1024;
        short8 bh = *(const short8*)p;
        short8 bl = *(const short8*)(p + 32768);
        acc[cg] = __builtin_amdgcn_mfma_f32_16x16x32_bf16(ahi[st], bh, acc[cg], 0, 0, 0);
        acc[cg] = __builtin_amdgcn_mfma_f32_16x16x32_bf16(alo[st], bh, acc[cg], 0, 0, 0);
        acc[cg] = __builtin_amdgcn_mfma_f32_16x16x32_bf16(ahi[st], bl, acc[cg], 0, 0, 0);
      }
    }

    // dist = cn - 2*dot; per-row top-2 (ascending k => strict '<' keeps first)
#pragma unroll
    for (int cg = 0; cg < 2; ++cg) {
      int k = ti * 64 + ch * 32 + cg * 16 + col;
      float cn = cn32[k];
#pragma unroll
      for (int r = 0; r < 4; ++r) {
        float dist = fmaf(-2.f, acc[cg][r], cn);
        if (dist < v1[r]) { v2[r] = v1[r]; v1[r] = dist; i1[r] = k; }
        else              { v2[r] = fminf(v2[r], dist); }
      }
    }
    __syncthreads();
    cur ^= 1;
  }

  // ---- merge top-2 across the 16 col-lanes ----
#pragma unroll
  for (int r = 0; r < 4; ++r) {
    float a1 = v1[r], a2 = v2[r]; int ai = i1[r];
#pragma unroll
    for (int off = 1; off < 16; off <<= 1) {
      float o1 = __shfl_xor(a1, off, 64);
      float o2 = __shfl_xor(a2, off, 64);
      int   oi = __shfl_xor(ai, off, 64);
      if (o1 < a1 || (o1 == a1 && oi < ai)) { a2 = fminf(a1, o2); a1 = o1; ai = oi; }
      else                                  { a2 = fminf(a2, o1); }
    }
    v1[r] = a1; v2[r] = a2; i1[r] = ai;
  }
  if (col == 0) {
#pragma unroll
    for (int r = 0; r < 4; ++r) {
      m1[wid][kg * 4 + r] = v1[r];
      m2[wid][kg * 4 + r] = v2[r];
      mi[wid][kg * 4 + r] = i1[r];
    }
  }
  __syncthreads();

  // ---- merge code-halves; flag near-ties; write indices ----
  if (t < 64) {
    int rgg = t >> 4, li = t & 15;
    float a1 = m1[rgg][li], a2 = m2[rgg][li]; int ai = mi[rgg][li];
    float o1 = m1[rgg + 4][li], o2 = m2[rgg + 4][li]; int oi = mi[rgg + 4][li];
    if (o1 < a1 || (o1 == a1 && oi < ai)) { a2 = fminf(a1, o2); a1 = o1; ai = oi; }
    else                                  { a2 = fminf(a2, o1); }
    bool flag = (a2 - a1) < THRESH;
    sIdx[t] = ai;
    idxws[g0 + t] = flag ? -(ai + 1) : ai;
    out[IDXOFF + g0 + t] = (float)ai;
    if (flag) { int p = atomicAdd(rcount, 1); if (p < RCAP) rlist[p] = g0 + t; }
  }
  __syncthreads();

  // ---- gather winning codebook rows into LDS (stride 257 => conflict-free cols)
  float* qt = (float*)&tiles[0][0];
  {
    int r = t >> 3, seg = t & 7;
    const float4* cp = (const float4*)(cb + (size_t)sIdx[r] * DIM + seg * 32);
#pragma unroll
    for (int i = 0; i < 8; ++i) {
      float4 v = cp[i];
      int d = seg * 32 + i * 4;
      qt[r * 257 + d]     = v.x;
      qt[r * 257 + d + 1] = v.y;
      qt[r * 257 + d + 2] = v.z;
      qt[r * 257 + d + 3] = v.w;
    }
  }
  __syncthreads();

  // ---- quantized write (256B coalesced) + commitment loss ----
  float lsum = 0.f;
  {
    int r = t & 63, part = t >> 6;
    const float* xp = x   + (size_t)((b << 8) + part * 32) * NSEQ + n0 + r;
    float*       op = out + (size_t)((b << 8) + part * 32) * NSEQ + n0 + r;
#pragma unroll
    for (int i = 0; i < 32; ++i) {
      float qv = qt[r * 257 + part * 32 + i];
      float xv = xp[(size_t)i * NSEQ];
      op[(size_t)i * NSEQ] = qv;
      float dx = qv - xv;
      lsum = fmaf(dx, dx, lsum);
    }
  }
#pragma unroll
  for (int off = 32; off > 0; off >>= 1) lsum += __shfl_xor(lsum, off, 64);
  if (l == 0) wl[wid] = (double)lsum;
  __syncthreads();
  if (t == 0) {
    double s = 0.0;
#pragma unroll
    for (int w = 0; w < 8; ++w) s += wl[w];
    atomicAdd(wsloss, s);
  }
}

// -------- rescreen: exact f64 argmin for flagged rows, fix outputs ---------
__global__ __launch_bounds__(256) void fsq_rescreen(
    const float* __restrict__ x, const float* __restrict__ cb,
    const double* __restrict__ cn64, const int* __restrict__ rcount,
    const int* __restrict__ rlist, const int* __restrict__ idxws,
    float* __restrict__ out, double* __restrict__ wsloss) {
  __shared__ float  xrow[DIM];
  __shared__ double rv[4];
  __shared__ int    ri[4];
  __shared__ int    sBi;
  __shared__ double dl[4];

  const int t    = threadIdx.x;
  const int lane = t & 63;
  const int wv   = t >> 6;
  int cnt = *rcount;
  if (cnt > RCAP) cnt = RCAP;
  if (cnt < 0) cnt = 0;

  for (int i = blockIdx.x; i < cnt; i += gridDim.x) {
    const int row = rlist[i] & 16383;
    const int b   = row >> 11;
    const int n   = row & (NSEQ - 1);
    xrow[t] = x[((size_t)(b << 8) + t) * NSEQ + n];
    __syncthreads();

    double best = DBL_MAX;
    int    bi   = 0;
    const float4* xr = reinterpret_cast<const float4*>(&xrow[0]);
#pragma unroll 1
    for (int c = 0; c < 16; ++c) {
      int k = t + (c << 8);
      const float4* cp = reinterpret_cast<const float4*>(cb + (size_t)k * DIM);
      double dot = 0.0;
#pragma unroll 4
      for (int d4 = 0; d4 < DIM / 4; ++d4) {
        float4 cv = cp[d4];
        float4 xv = xr[d4];
        dot += (double)xv.x * cv.x + (double)xv.y * cv.y +
               (double)xv.z * cv.z + (double)xv.w * cv.w;
      }
      double dist = cn64[k] - 2.0 * dot;
      if (dist < best || (dist == best && k < bi)) { best = dist; bi = k; }
    }
#pragma unroll
    for (int off = 1; off < 64; off <<= 1) {
      double ob = __shfl_xor(best, off, 64);
      int    oi = __shfl_xor(bi, off, 64);
      if (ob < best || (ob == best && oi < bi)) { best = ob; bi = oi; }
    }
    if (lane == 0) { rv[wv] = best; ri[wv] = bi; }
    __syncthreads();
    if (t == 0) {
      double bb = rv[0]; int ii = ri[0];
#pragma unroll
      for (int w = 1; w < 4; ++w)
        if (rv[w] < bb || (rv[w] == bb && ri[w] < ii)) { bb = rv[w]; ii = ri[w]; }
      sBi = ii;
    }
    __syncthreads();

    int enc = idxws[row];
    int old = (enc < 0) ? -(enc + 1) : enc;
    int nw  = sBi;
    if (nw != old) {
      // fix index, quantized column, and loss delta
      if (t == 0) out[IDXOFF + row] = (float)nw;
      float qn = cb[(size_t)nw  * DIM + t];
      float qo = cb[(size_t)old * DIM + t];
      float xv = xrow[t];
      out[((size_t)(b << 8) + t) * NSEQ + n] = qn;
      float d1 = qn - xv, d0 = qo - xv;
      float delta = d1 * d1 - d0 * d0;
#pragma unroll
      for (int off = 32; off > 0; off >>= 1) delta += __shfl_xor(delta, off, 64);
      if (lane == 0) dl[wv] = (double)delta;
      __syncthreads();
      if (t == 0) atomicAdd(wsloss, dl[0] + dl[1] + dl[2] + dl[3]);
    }
    __syncthreads();
  }
}

__global__ void fsq_finish(const double* __restrict__ wsloss, float* __restrict__ out) {
  if (threadIdx.x == 0)
    out[LOSS_OFF] = (float)(*wsloss * (0.25 / 4194304.0));
}

extern "C" void kernel_launch(void* const* d_in, const int* in_sizes, int n_in,
                              void* d_out, int out_size, void* d_ws, size_t ws_size,
                              hipStream_t stream) {
  const float* x  = (const float*)d_in[0];   // [8, 256, 2048]
  const float* cb = (const float*)d_in[1];   // [4096, 256]
  float* out = (float*)d_out;

  char* wsb = (char*)d_ws;
  double* wsloss = (double*)wsb;                    // @0
  int*    rcount = (int*)(wsb + 8);                 // @8
  float*  cn32   = (float*)(wsb + 4096);            // 16 KB
  double* cn64   = (double*)(wsb + 4096 + 16384);   // 32 KB
  int*    idxws  = (int*)(wsb + 4096 + 16384 + 32768);            // 64 KB
  int*    rlist  = (int*)(wsb + 4096 + 16384 + 32768 + 65536);    // 4 KB
  char*   cbsplit = wsb + 131072;                   // 4 MB, tile-fragment order

  fsq_prep<<<KCODES / 256, 256, 0, stream>>>(cb, cn32, cn64, wsloss, rcount);
  fsq_perm<<<512, 256, 0, stream>>>(cb, cbsplit);
  fsq_score<<<256, 512, 0, stream>>>(x, cb, cbsplit, cn32, idxws, rcount, rlist, out, wsloss);
  fsq_rescreen<<<256, 256, 0, stream>>>(x, cb, cn64, rcount, rlist, idxws, out, wsloss);
  fsq_finish<<<1, 64, 0, stream>>>(wsloss, out);
}